// Round 1
// baseline (398.337 us; speedup 1.0000x reference)
//
#include <hip/hip_runtime.h>
#include <math.h>

#define B_  8
#define T_  8192
#define T2_ 4096
#define F_  512
#define F2_ 256
#define K_  8

typedef unsigned long long u64;
typedef float fvec2 __attribute__((ext_vector_type(2)));

// Sorted-descending top-8 insert of packed key (abs_bits<<32)|~t2.
// Keys unique (t2 unique); ~t2 gives lower-index-first on equal abs,
// matching jax.lax.top_k.
__device__ __forceinline__ void ins8(u64 (&a)[K_], u64 k) {
    if (k <= a[K_ - 1]) return;
#pragma unroll
    for (int j = 0; j < K_; ++j) {
        u64 hi = (k > a[j]) ? k : a[j];
        u64 lo = (k > a[j]) ? a[j] : k;
        a[j] = hi;
        k = lo;
    }
}

// Phase 1: stream x once (float2 lanes over f; 2 f-columns/thread so the grid
// is 2x wider -> 4 waves/SIMD instead of 2, hiding HBM latency). Write main
// twice-interleaved AND zero the detail rows in the same pass (NT stores:
// never re-read; replaces the 165us serialized memset). Emit per-(col,slot)
// top-8 candidate keys.
__global__ __launch_bounds__(256) void haar_phase1(
    const fvec2* __restrict__ x2, fvec2* __restrict__ mainOut,
    fvec2* __restrict__ detOut, u64* __restrict__ cand, int S, int L)
{
    const int tx   = threadIdx.x;
    const int f2   = blockIdx.x * 64 + tx;            // 0..255
    const int slot = blockIdx.y * 4 + threadIdx.y;    // 0..S-1
    const int b    = blockIdx.z;
    const int t2_0 = slot * L;

    u64 a0[K_], a1[K_];
#pragma unroll
    for (int j = 0; j < K_; ++j) { a0[j] = 0; a1[j] = 0; }

    const size_t rowBase = (size_t)b * T_;
    const fvec2 z = (fvec2)0.0f;

#pragma unroll 2
    for (int t = 0; t < L; ++t) {
        const int t2 = t2_0 + t;
        const size_t re = (rowBase + 2 * (size_t)t2) * F2_ + f2;  // even row
        fvec2 e = x2[re];
        fvec2 o = x2[re + F2_];
        fvec2 low = (e + o) * 0.5f;
        __builtin_nontemporal_store(low, &mainOut[re]);
        __builtin_nontemporal_store(low, &mainOut[re + F2_]);
        __builtin_nontemporal_store(z, &detOut[re]);
        __builtin_nontemporal_store(z, &detOut[re + F2_]);
        const u64 it = (u64)(unsigned)(~t2);
        ins8(a0, ((u64)__float_as_uint(fabsf(e.x - o.x)) << 32) | it);
        ins8(a1, ((u64)__float_as_uint(fabsf(e.y - o.y)) << 32) | it);
    }

    // cand layout: (col * S + slot) * 8 + j, col = b*F + f. 64B line per list.
    const size_t colBase = (size_t)b * F_ + 2 * (size_t)f2;
    u64* d0 = cand + ((colBase + 0) * S + slot) * K_;
    u64* d1 = cand + ((colBase + 1) * S + slot) * K_;
#pragma unroll
    for (int j = 0; j < K_; ++j) { d0[j] = a0[j]; d1[j] = a1[j]; }
}

// Phase 2: one wave per column. Coalesced candidate reads, per-lane top-8,
// 8 rounds of wave-wide u64 argmax, then lanes 0..7 scatter the winners.
// Runs after phase1, so the detail zeros are already in place.
__global__ __launch_bounds__(256) void haar_phase2(
    const float* __restrict__ x, const u64* __restrict__ cand,
    float* __restrict__ out, int S)
{
    const int lane = threadIdx.x & 63;
    const int wv   = threadIdx.x >> 6;
    const int col  = blockIdx.x * 4 + wv;      // b*F + f
    const int b    = col >> 9;
    const int f    = col & (F_ - 1);
    const int n    = S * K_;                   // candidates per column

    const u64* c = cand + (size_t)col * n;
    u64 a[K_];
#pragma unroll
    for (int j = 0; j < K_; ++j) a[j] = 0;
    for (int e = lane; e < n; e += 64) ins8(a, c[e]);

    u64 wkey = 0;
#pragma unroll
    for (int j = 0; j < K_; ++j) {
        u64 m = a[0];
#pragma unroll
        for (int s = 32; s > 0; s >>= 1) {
            u64 t = __shfl_xor(m, s, 64);
            m = (t > m) ? t : m;
        }
        if (a[0] == m) {            // exactly one lane (keys unique)
#pragma unroll
            for (int q = 0; q < K_ - 1; ++q) a[q] = a[q + 1];
            a[K_ - 1] = 0;
        }
        if (lane == j) wkey = m;
    }

    float* det = out + (size_t)B_ * T_ * F_;
    if (lane < K_) {
        const int t2 = (int)(~(unsigned)wkey);
        const size_t re = ((size_t)b * T_ + 2 * (size_t)t2) * F_ + f;
        const float e = x[re];
        const float o = x[re + F_];
        const float v = (e - o) * 0.5f;
        det[re]      = v;
        det[re + F_] = -v;
    }
}

extern "C" void kernel_launch(void* const* d_in, const int* in_sizes, int n_in,
                              void* d_out, int out_size, void* d_ws, size_t ws_size,
                              hipStream_t stream) {
    const float* x = (const float*)d_in[0];
    float* out = (float*)d_out;
    float* detail = out + (size_t)B_ * T_ * F_;

    // Workspace: B*F*S*K u64 keys. S=128: 34 MB cand, 1024 phase-1 blocks.
    int S = 128;
    while (S > 32 && (size_t)B_ * F_ * (size_t)S * K_ * sizeof(u64) > ws_size) S >>= 1;
    const int L = T2_ / S;
    u64* cand = (u64*)d_ws;

    dim3 gA(F2_ / 64, S / 4, B_);
    dim3 bA(64, 4, 1);
    hipLaunchKernelGGL(haar_phase1, gA, bA, 0, stream,
                       (const fvec2*)x, (fvec2*)out, (fvec2*)detail, cand, S, L);

    const int nb = (B_ * F_) / 4;   // one wave per column, 4 waves/block
    hipLaunchKernelGGL(haar_phase2, dim3(nb), dim3(256), 0, stream,
                       x, cand, out, S);
}

// Round 2
// 397.743 us; speedup vs baseline: 1.0015x; 1.0015x over previous
//
#include <hip/hip_runtime.h>
#include <math.h>

#define B_  8
#define T_  8192
#define T2_ 4096
#define F_  512
#define F2_ 256
#define K_  8

typedef unsigned long long u64;
typedef float fvec2 __attribute__((ext_vector_type(2)));

// Sorted-descending top-8 insert of packed key (abs_bits<<32)|~t2.
// Keys unique (t2 unique); ~t2 gives lower-index-first on equal abs,
// matching jax.lax.top_k.
__device__ __forceinline__ void ins8(u64 (&a)[K_], u64 k) {
    if (k <= a[K_ - 1]) return;
#pragma unroll
    for (int j = 0; j < K_; ++j) {
        u64 hi = (k > a[j]) ? k : a[j];
        u64 lo = (k > a[j]) ? a[j] : k;
        a[j] = hi;
        k = lo;
    }
}

// Phase 1: stream x once. Software-pipelined: the NEXT iteration's loads are
// issued BEFORE the current iteration's stores, so the s_waitcnt consuming
// the loads does not have to drain store acks (vmcnt retires in order).
// Stores are PLAIN (not nontemporal): NT stores ack from the memory
// controller at HBM latency and gate the in-order vmcnt; plain stores ack
// from L2 and drain asynchronously (the 6.5 TB/s fill kernel proves this
// path reaches full BW).
__global__ __launch_bounds__(256) void haar_phase1(
    const fvec2* __restrict__ x2, fvec2* __restrict__ mainOut,
    fvec2* __restrict__ detOut, u64* __restrict__ cand, int S, int L)
{
    const int tx   = threadIdx.x;
    const int f2   = blockIdx.x * 64 + tx;            // 0..255
    const int slot = blockIdx.y * 4 + threadIdx.y;    // 0..S-1
    const int b    = blockIdx.z;
    const int t2_0 = slot * L;

    u64 a0[K_], a1[K_];
#pragma unroll
    for (int j = 0; j < K_; ++j) { a0[j] = 0; a1[j] = 0; }

    const size_t rowBase = (size_t)b * T_;
    const fvec2 z = {0.0f, 0.0f};

    // prologue: loads for t = 0
    size_t reNext = (rowBase + 2 * (size_t)t2_0) * F2_ + f2;
    fvec2 e = x2[reNext];
    fvec2 o = x2[reNext + F2_];

#pragma unroll 4
    for (int t = 0; t < L; ++t) {
        const size_t re = reNext;
        fvec2 e2, o2;
        if (t + 1 < L) {                 // issue next loads FIRST
            reNext = re + 2 * F2_;
            e2 = x2[reNext];
            o2 = x2[reNext + F2_];
        }
        const fvec2 low = (e + o) * 0.5f;
        mainOut[re]        = low;
        mainOut[re + F2_]  = low;
        detOut[re]         = z;
        detOut[re + F2_]   = z;
        const u64 it = (u64)(unsigned)(~(t2_0 + t));
        ins8(a0, ((u64)__float_as_uint(fabsf(e.x - o.x)) << 32) | it);
        ins8(a1, ((u64)__float_as_uint(fabsf(e.y - o.y)) << 32) | it);
        e = e2; o = o2;
    }

    // cand layout: (col * S + slot) * 8 + j, col = b*F + f. 64B line per list.
    const size_t colBase = (size_t)b * F_ + 2 * (size_t)f2;
    u64* d0 = cand + ((colBase + 0) * S + slot) * K_;
    u64* d1 = cand + ((colBase + 1) * S + slot) * K_;
#pragma unroll
    for (int j = 0; j < K_; ++j) { d0[j] = a0[j]; d1[j] = a1[j]; }
}

// Phase 2: one wave per column. Coalesced candidate reads, per-lane top-8,
// 8 rounds of wave-wide u64 argmax, then lanes 0..7 scatter the winners.
// Runs after phase1, so the detail zeros are already in place.
__global__ __launch_bounds__(256) void haar_phase2(
    const float* __restrict__ x, const u64* __restrict__ cand,
    float* __restrict__ out, int S)
{
    const int lane = threadIdx.x & 63;
    const int wv   = threadIdx.x >> 6;
    const int col  = blockIdx.x * 4 + wv;      // b*F + f
    const int b    = col >> 9;
    const int f    = col & (F_ - 1);
    const int n    = S * K_;                   // candidates per column

    const u64* c = cand + (size_t)col * n;
    u64 a[K_];
#pragma unroll
    for (int j = 0; j < K_; ++j) a[j] = 0;
    for (int e = lane; e < n; e += 64) ins8(a, c[e]);

    u64 wkey = 0;
#pragma unroll
    for (int j = 0; j < K_; ++j) {
        u64 m = a[0];
#pragma unroll
        for (int s = 32; s > 0; s >>= 1) {
            u64 t = __shfl_xor(m, s, 64);
            m = (t > m) ? t : m;
        }
        if (a[0] == m) {            // exactly one lane (keys unique)
#pragma unroll
            for (int q = 0; q < K_ - 1; ++q) a[q] = a[q + 1];
            a[K_ - 1] = 0;
        }
        if (lane == j) wkey = m;
    }

    float* det = out + (size_t)B_ * T_ * F_;
    if (lane < K_) {
        const int t2 = (int)(~(unsigned)wkey);
        const size_t re = ((size_t)b * T_ + 2 * (size_t)t2) * F_ + f;
        const float e = x[re];
        const float o = x[re + F_];
        const float v = (e - o) * 0.5f;
        det[re]      = v;
        det[re + F_] = -v;
    }
}

extern "C" void kernel_launch(void* const* d_in, const int* in_sizes, int n_in,
                              void* d_out, int out_size, void* d_ws, size_t ws_size,
                              hipStream_t stream) {
    const float* x = (const float*)d_in[0];
    float* out = (float*)d_out;
    float* detail = out + (size_t)B_ * T_ * F_;

    // Workspace: B*F*S*K u64 keys. S=128: 34 MB cand, 1024 phase-1 blocks.
    int S = 128;
    while (S > 32 && (size_t)B_ * F_ * (size_t)S * K_ * sizeof(u64) > ws_size) S >>= 1;
    const int L = T2_ / S;
    u64* cand = (u64*)d_ws;

    dim3 gA(F2_ / 64, S / 4, B_);
    dim3 bA(64, 4, 1);
    hipLaunchKernelGGL(haar_phase1, gA, bA, 0, stream,
                       (const fvec2*)x, (fvec2*)out, (fvec2*)detail, cand, S, L);

    const int nb = (B_ * F_) / 4;   // one wave per column, 4 waves/block
    hipLaunchKernelGGL(haar_phase2, dim3(nb), dim3(256), 0, stream,
                       x, cand, out, S);
}